// Round 2
// baseline (4600.487 us; speedup 1.0000x reference)
//
#include <hip/hip_runtime.h>
#include <math.h>

#define F_IN 1433
#define F_HID 16
#define F_OUT 7
#define KT 32

// ---------------- init: zero accumulators, deg=1 (self-loop) ----------------
__global__ __launch_bounds__(256) void k_init(float* __restrict__ acc1,
                                              float* __restrict__ acc2,
                                              float* __restrict__ deg, int N) {
  int i = blockIdx.x * 256 + threadIdx.x;
  if (i < N * F_HID) acc1[i] = 0.0f;
  if (i < N * F_OUT) acc2[i] = 0.0f;
  if (i < N) deg[i] = 1.0f;  // self-loop contributes 1 to in-degree
}

// ---------------- degree accumulation over real edges ----------------
__global__ __launch_bounds__(256) void k_deg(const int* __restrict__ dst,
                                             float* __restrict__ deg, int E) {
  int e = blockIdx.x * 256 + threadIdx.x;
  if (e < E) atomicAdd(&deg[dst[e]], 1.0f);
}

__global__ __launch_bounds__(256) void k_rsqrt(float* __restrict__ deg, int N) {
  int i = blockIdx.x * 256 + threadIdx.x;
  if (i < N) deg[i] = 1.0f / sqrtf(deg[i]);  // deg >= 1 always
}

// ---------------- GEMM1: h1s[row][j] = dis[row] * sum_k x[row][k]*W1[k][j] ----
// 256 rows per block, one row per thread, 16 output cols in registers.
// x staged per K-tile in LDS [256][33] (pad -> conflict-free).
// W1 row address is wave-uniform -> compiler emits scalar loads.
__global__ __launch_bounds__(256) void k_gemm1(const float* __restrict__ x,
                                               const float* __restrict__ W1,
                                               const float* __restrict__ dis,
                                               float* __restrict__ h1s, int N) {
  __shared__ float xs[256 * 33];
  const int t = threadIdx.x;
  const int row0 = blockIdx.x * 256;
  const int row = row0 + t;
  const int kk = t & 31;
  const int r0 = t >> 5;

  float acc[F_HID];
#pragma unroll
  for (int j = 0; j < F_HID; ++j) acc[j] = 0.0f;

  for (int k0 = 0; k0 < F_IN; k0 += KT) {
    const int kw = min(KT, F_IN - k0);
    // stage 256 rows x kw cols, coalesced along k
#pragma unroll
    for (int i = 0; i < 32; ++i) {
      const int rl = r0 + 8 * i;
      const int rg = row0 + rl;
      float v = 0.0f;
      if (kk < kw && rg < N) v = x[rg * F_IN + k0 + kk];
      xs[rl * 33 + kk] = v;
    }
    __syncthreads();
    const float* __restrict__ wp = W1 + k0 * F_HID;
    for (int c = 0; c < kw; ++c) {
      const float xv = xs[t * 33 + c];
#pragma unroll
      for (int j = 0; j < F_HID; ++j)
        acc[j] = fmaf(xv, wp[c * F_HID + j], acc[j]);
    }
    __syncthreads();
  }

  if (row < N) {
    const float s = dis[row];
    float4* __restrict__ hp = (float4*)(h1s + (size_t)row * F_HID);
    hp[0] = make_float4(acc[0] * s, acc[1] * s, acc[2] * s, acc[3] * s);
    hp[1] = make_float4(acc[4] * s, acc[5] * s, acc[6] * s, acc[7] * s);
    hp[2] = make_float4(acc[8] * s, acc[9] * s, acc[10] * s, acc[11] * s);
    hp[3] = make_float4(acc[12] * s, acc[13] * s, acc[14] * s, acc[15] * s);
  }
}

// ---------------- edge scatter layer 1: acc1[dst] += h1s[src] ----------------
__global__ __launch_bounds__(256) void k_agg1(const int* __restrict__ src,
                                              const int* __restrict__ dst,
                                              const float* __restrict__ h1s,
                                              float* __restrict__ acc1, int E) {
  int e = blockIdx.x * 256 + threadIdx.x;
  if (e >= E) return;
  const int s = src[e];
  const int d = dst[e];
  const float4* __restrict__ hp = (const float4*)(h1s + (size_t)s * F_HID);
  const float4 v0 = hp[0], v1 = hp[1], v2 = hp[2], v3 = hp[3];
  float* __restrict__ op = acc1 + (size_t)d * F_HID;
  atomicAdd(op + 0, v0.x);  atomicAdd(op + 1, v0.y);
  atomicAdd(op + 2, v0.z);  atomicAdd(op + 3, v0.w);
  atomicAdd(op + 4, v1.x);  atomicAdd(op + 5, v1.y);
  atomicAdd(op + 6, v1.z);  atomicAdd(op + 7, v1.w);
  atomicAdd(op + 8, v2.x);  atomicAdd(op + 9, v2.y);
  atomicAdd(op + 10, v2.z); atomicAdd(op + 11, v2.w);
  atomicAdd(op + 12, v3.x); atomicAdd(op + 13, v3.y);
  atomicAdd(op + 14, v3.z); atomicAdd(op + 15, v3.w);
}

// ------- node kernel: t = relu((acc1+h1s)*dis + b1); h2s = (t @ W2) * dis ----
__global__ __launch_bounds__(256) void k_node1(const float* __restrict__ acc1,
                                               const float* __restrict__ h1s,
                                               const float* __restrict__ dis,
                                               const float* __restrict__ b1,
                                               const float* __restrict__ W2,
                                               float* __restrict__ h2s, int N) {
  int i = blockIdx.x * 256 + threadIdx.x;
  if (i >= N) return;
  const float s = dis[i];
  const float4* __restrict__ ap = (const float4*)(acc1 + (size_t)i * F_HID);
  const float4* __restrict__ hp = (const float4*)(h1s + (size_t)i * F_HID);
  float tv[F_HID];
#pragma unroll
  for (int q = 0; q < 4; ++q) {
    const float4 a = ap[q];
    const float4 h = hp[q];
    tv[4 * q + 0] = fmaxf(fmaf(a.x + h.x, s, b1[4 * q + 0]), 0.0f);
    tv[4 * q + 1] = fmaxf(fmaf(a.y + h.y, s, b1[4 * q + 1]), 0.0f);
    tv[4 * q + 2] = fmaxf(fmaf(a.z + h.z, s, b1[4 * q + 2]), 0.0f);
    tv[4 * q + 3] = fmaxf(fmaf(a.w + h.w, s, b1[4 * q + 3]), 0.0f);
  }
  float o[F_OUT];
#pragma unroll
  for (int j = 0; j < F_OUT; ++j) o[j] = 0.0f;
#pragma unroll
  for (int k = 0; k < F_HID; ++k) {
    const float v = tv[k];
#pragma unroll
    for (int j = 0; j < F_OUT; ++j) o[j] = fmaf(v, W2[k * F_OUT + j], o[j]);
  }
  float* __restrict__ out = h2s + (size_t)i * F_OUT;
#pragma unroll
  for (int j = 0; j < F_OUT; ++j) out[j] = o[j] * s;
}

// ---------------- edge scatter layer 2: acc2[dst] += h2s[src] ----------------
__global__ __launch_bounds__(256) void k_agg2(const int* __restrict__ src,
                                              const int* __restrict__ dst,
                                              const float* __restrict__ h2s,
                                              float* __restrict__ acc2, int E) {
  int e = blockIdx.x * 256 + threadIdx.x;
  if (e >= E) return;
  const int s = src[e];
  const int d = dst[e];
  const float* __restrict__ hp = h2s + (size_t)s * F_OUT;
  float* __restrict__ op = acc2 + (size_t)d * F_OUT;
#pragma unroll
  for (int j = 0; j < F_OUT; ++j) atomicAdd(op + j, hp[j]);
}

// ------- final: v = (acc2 + h2s)*dis + b2 ; out = log_softmax(v) -------------
__global__ __launch_bounds__(256) void k_node2(float* __restrict__ acc2_out,
                                               const float* __restrict__ h2s,
                                               const float* __restrict__ dis,
                                               const float* __restrict__ b2,
                                               int N) {
  int i = blockIdx.x * 256 + threadIdx.x;
  if (i >= N) return;
  const float s = dis[i];
  float v[F_OUT];
  float m = -1e30f;
#pragma unroll
  for (int j = 0; j < F_OUT; ++j) {
    v[j] = fmaf(acc2_out[(size_t)i * F_OUT + j] + h2s[(size_t)i * F_OUT + j], s,
                b2[j]);
    m = fmaxf(m, v[j]);
  }
  float sum = 0.0f;
#pragma unroll
  for (int j = 0; j < F_OUT; ++j) sum += expf(v[j] - m);
  const float l = logf(sum);
#pragma unroll
  for (int j = 0; j < F_OUT; ++j) acc2_out[(size_t)i * F_OUT + j] = v[j] - m - l;
}

extern "C" void kernel_launch(void* const* d_in, const int* in_sizes, int n_in,
                              void* d_out, int out_size, void* d_ws,
                              size_t ws_size, hipStream_t stream) {
  const float* x = (const float*)d_in[0];
  const int* ei = (const int*)d_in[1];
  const float* W1 = (const float*)d_in[2];
  const float* b1 = (const float*)d_in[3];
  const float* W2 = (const float*)d_in[4];
  const float* b2 = (const float*)d_in[5];

  const int N = in_sizes[0] / F_IN;
  const int E = in_sizes[1] / 2;
  const int* src = ei;
  const int* dst = ei + E;

  float* ws = (float*)d_ws;
  float* deg = ws;                  // N floats (becomes dis after k_rsqrt)
  float* h1s = deg + N;             // 16N
  float* acc1 = h1s + 16 * N;       // 16N
  float* h2s = acc1 + 16 * N;       // 7N
  float* out = (float*)d_out;       // 7N: layer-2 accumulator, then final

  const int B = 256;
  k_init<<<(N * F_HID + B - 1) / B, B, 0, stream>>>(acc1, out, deg, N);
  k_deg<<<(E + B - 1) / B, B, 0, stream>>>(dst, deg, E);
  k_rsqrt<<<(N + B - 1) / B, B, 0, stream>>>(deg, N);
  k_gemm1<<<(N + 255) / 256, 256, 0, stream>>>(x, W1, deg, h1s, N);
  k_agg1<<<(E + B - 1) / B, B, 0, stream>>>(src, dst, h1s, acc1, E);
  k_node1<<<(N + B - 1) / B, B, 0, stream>>>(acc1, h1s, deg, b1, W2, h2s, N);
  k_agg2<<<(E + B - 1) / B, B, 0, stream>>>(src, dst, h2s, out, E);
  k_node2<<<(N + B - 1) / B, B, 0, stream>>>(out, h2s, deg, b2, N);
}

// Round 3
// 1237.183 us; speedup vs baseline: 3.7185x; 3.7185x over previous
//
#include <hip/hip_runtime.h>
#include <math.h>

#define F_IN 1433
#define F_HID 16
#define F_OUT 7
#define KT 32

// ---------------- zero int counters ----------------
__global__ __launch_bounds__(256) void k_zero(int* __restrict__ cnt, int N) {
  int i = blockIdx.x * 256 + threadIdx.x;
  if (i < N) cnt[i] = 0;
}

// ---------------- in-degree histogram over real edges ----------------
__global__ __launch_bounds__(256) void k_hist(const int* __restrict__ dst,
                                              int* __restrict__ cnt, int E) {
  int e = blockIdx.x * 256 + threadIdx.x;
  if (e < E) atomicAdd(&cnt[dst[e]], 1);
}

// ---------------- scan step 1: per-1024-block exclusive scan ----------------
__global__ __launch_bounds__(256) void k_scan1(const int* __restrict__ cnt,
                                               int* __restrict__ offs,
                                               int* __restrict__ bsums, int N) {
  __shared__ int sh[256];
  const int b = blockIdx.x, t = threadIdx.x;
  const int base = b * 1024 + t * 4;
  int v0 = 0, v1 = 0, v2 = 0, v3 = 0;
  if (base + 0 < N) v0 = cnt[base + 0];
  if (base + 1 < N) v1 = cnt[base + 1];
  if (base + 2 < N) v2 = cnt[base + 2];
  if (base + 3 < N) v3 = cnt[base + 3];
  const int s = v0 + v1 + v2 + v3;
  sh[t] = s;
  __syncthreads();
  for (int d = 1; d < 256; d <<= 1) {
    int x = (t >= d) ? sh[t - d] : 0;
    __syncthreads();
    sh[t] += x;
    __syncthreads();
  }
  const int incl = sh[t];
  const int excl = incl - s;
  if (t == 255) bsums[b] = incl;
  int o = excl;
  if (base + 0 < N) offs[base + 0] = o;
  o += v0;
  if (base + 1 < N) offs[base + 1] = o;
  o += v1;
  if (base + 2 < N) offs[base + 2] = o;
  o += v2;
  if (base + 3 < N) offs[base + 3] = o;
}

// ---------------- scan step 2: scan the block sums (1 block) ----------------
__global__ __launch_bounds__(1024) void k_scan2(int* __restrict__ bsums, int nb) {
  __shared__ int sh[1024];
  const int t = threadIdx.x;
  const int v = (t < nb) ? bsums[t] : 0;
  sh[t] = v;
  __syncthreads();
  for (int d = 1; d < 1024; d <<= 1) {
    int x = (t >= d) ? sh[t - d] : 0;
    __syncthreads();
    sh[t] += x;
    __syncthreads();
  }
  if (t < nb) bsums[t] = sh[t] - v;  // exclusive
}

// ---- scan step 3: finalize offsets, init cursor, dis = rsqrt(deg+1) --------
__global__ __launch_bounds__(256) void k_scan3(int* __restrict__ offs,
                                               int* __restrict__ cursor,
                                               float* __restrict__ dis,
                                               const int* __restrict__ cnt,
                                               const int* __restrict__ bsums,
                                               int N) {
  int i = blockIdx.x * 256 + threadIdx.x;
  if (i >= N) return;
  const int o = offs[i] + bsums[i >> 10];
  offs[i] = o;
  cursor[i] = o;
  dis[i] = rsqrtf((float)(cnt[i] + 1));  // +1 = self-loop
}

// ---------------- CSR scatter: csr[slot] = src, grouped by dst --------------
__global__ __launch_bounds__(256) void k_scatter(const int* __restrict__ src,
                                                 const int* __restrict__ dst,
                                                 int* __restrict__ cursor,
                                                 int* __restrict__ csr, int E) {
  int e = blockIdx.x * 256 + threadIdx.x;
  if (e >= E) return;
  const int d = dst[e];
  const int p = atomicAdd(&cursor[d], 1);
  csr[p] = src[e];
}

// ---------------- GEMM1: h1s[row][j] = dis[row] * sum_k x[row][k]*W1[k][j] ----
__global__ __launch_bounds__(256) void k_gemm1(const float* __restrict__ x,
                                               const float* __restrict__ W1,
                                               const float* __restrict__ dis,
                                               float* __restrict__ h1s, int N) {
  __shared__ float xs[256 * 33];
  const int t = threadIdx.x;
  const int row0 = blockIdx.x * 256;
  const int row = row0 + t;
  const int kk = t & 31;
  const int r0 = t >> 5;

  float acc[F_HID];
#pragma unroll
  for (int j = 0; j < F_HID; ++j) acc[j] = 0.0f;

  for (int k0 = 0; k0 < F_IN; k0 += KT) {
    const int kw = min(KT, F_IN - k0);
#pragma unroll
    for (int i = 0; i < 32; ++i) {
      const int rl = r0 + 8 * i;
      const int rg = row0 + rl;
      float v = 0.0f;
      if (kk < kw && rg < N) v = x[(size_t)rg * F_IN + k0 + kk];
      xs[rl * 33 + kk] = v;
    }
    __syncthreads();
    const float* __restrict__ wp = W1 + k0 * F_HID;
    for (int c = 0; c < kw; ++c) {
      const float xv = xs[t * 33 + c];
#pragma unroll
      for (int j = 0; j < F_HID; ++j)
        acc[j] = fmaf(xv, wp[c * F_HID + j], acc[j]);
    }
    __syncthreads();
  }

  if (row < N) {
    const float s = dis[row];
    float4* __restrict__ hp = (float4*)(h1s + (size_t)row * F_HID);
    hp[0] = make_float4(acc[0] * s, acc[1] * s, acc[2] * s, acc[3] * s);
    hp[1] = make_float4(acc[4] * s, acc[5] * s, acc[6] * s, acc[7] * s);
    hp[2] = make_float4(acc[8] * s, acc[9] * s, acc[10] * s, acc[11] * s);
    hp[3] = make_float4(acc[12] * s, acc[13] * s, acc[14] * s, acc[15] * s);
  }
}

// ---- layer1 gather + node update fused: one wave64 per dst node ------------
// lanes = 4 neighbor-groups x 16 features
__global__ __launch_bounds__(256) void k_agg1n(const int* __restrict__ offs,
                                               const int* __restrict__ cnt,
                                               const int* __restrict__ csr,
                                               const float* __restrict__ h1s,
                                               const float* __restrict__ dis,
                                               const float* __restrict__ b1,
                                               const float* __restrict__ W2,
                                               float* __restrict__ h2s, int N) {
  const int lane = threadIdx.x & 63;
  const int i = blockIdx.x * 4 + (threadIdx.x >> 6);
  if (i >= N) return;
  const int nb = lane >> 4;
  const int f = lane & 15;

  const int o0 = offs[i];
  const int d = cnt[i];
  float acc = 0.0f;
  for (int c = o0 + nb; c < o0 + d; c += 4) {
    const int s = csr[c];
    acc += h1s[(size_t)s * F_HID + f];
  }
  acc += __shfl_xor(acc, 16);
  acc += __shfl_xor(acc, 32);

  const float sd = dis[i];
  const float t = fmaxf(fmaf(acc + h1s[(size_t)i * F_HID + f], sd, b1[f]), 0.0f);

  float o[F_OUT];
#pragma unroll
  for (int j = 0; j < F_OUT; ++j) o[j] = t * W2[f * F_OUT + j];
#pragma unroll
  for (int dd = 1; dd < 16; dd <<= 1) {
#pragma unroll
    for (int j = 0; j < F_OUT; ++j) o[j] += __shfl_xor(o[j], dd);
  }
  if (lane == 0) {
    float* __restrict__ hp = h2s + (size_t)i * F_OUT;
#pragma unroll
    for (int j = 0; j < F_OUT; ++j) hp[j] = o[j] * sd;
  }
}

// ---- layer2 gather + bias + log_softmax fused: one wave64 per dst ----------
// lanes = 8 neighbor-groups x 8 feature slots (slot 7 inactive)
__global__ __launch_bounds__(256) void k_agg2n(const int* __restrict__ offs,
                                               const int* __restrict__ cnt,
                                               const int* __restrict__ csr,
                                               const float* __restrict__ h2s,
                                               const float* __restrict__ dis,
                                               const float* __restrict__ b2,
                                               float* __restrict__ out, int N) {
  const int lane = threadIdx.x & 63;
  const int i = blockIdx.x * 4 + (threadIdx.x >> 6);
  if (i >= N) return;
  const int nb = lane >> 3;
  const int f = lane & 7;

  const int o0 = offs[i];
  const int d = cnt[i];
  float acc = 0.0f;
  for (int c = o0 + nb; c < o0 + d; c += 8) {
    const int s = csr[c];
    if (f < F_OUT) acc += h2s[(size_t)s * F_OUT + f];
  }
  acc += __shfl_xor(acc, 8);
  acc += __shfl_xor(acc, 16);
  acc += __shfl_xor(acc, 32);

  float v = -1e30f;
  if (f < F_OUT)
    v = fmaf(acc + h2s[(size_t)i * F_OUT + f], dis[i], b2[f]);

  float m = v;
  m = fmaxf(m, __shfl_xor(m, 1));
  m = fmaxf(m, __shfl_xor(m, 2));
  m = fmaxf(m, __shfl_xor(m, 4));
  float ex = (f < F_OUT) ? expf(v - m) : 0.0f;
  float sum = ex;
  sum += __shfl_xor(sum, 1);
  sum += __shfl_xor(sum, 2);
  sum += __shfl_xor(sum, 4);
  const float r = v - m - logf(sum);
  if (f < F_OUT) out[(size_t)i * F_OUT + f] = r;
}

extern "C" void kernel_launch(void* const* d_in, const int* in_sizes, int n_in,
                              void* d_out, int out_size, void* d_ws,
                              size_t ws_size, hipStream_t stream) {
  const float* x = (const float*)d_in[0];
  const int* ei = (const int*)d_in[1];
  const float* W1 = (const float*)d_in[2];
  const float* b1 = (const float*)d_in[3];
  const float* W2 = (const float*)d_in[4];
  const float* b2 = (const float*)d_in[5];

  const int N = in_sizes[0] / F_IN;
  const int E = in_sizes[1] / 2;
  const int* src = ei;
  const int* dst = ei + E;

  // workspace layout (floats first for 16B alignment of h1s)
  float* h1s = (float*)d_ws;        // 16N
  float* h2s = h1s + (size_t)16 * N;  // 7N
  float* dis = h2s + (size_t)7 * N;   // N
  int* cnt = (int*)(dis + N);       // N
  int* offs = cnt + N;              // N
  int* cursor = offs + N;           // N
  int* bsums = cursor + N;          // 1024
  int* csr = bsums + 1024;          // E
  float* out = (float*)d_out;

  const int B = 256;
  const int nb_scan = (N + 1023) / 1024;

  k_zero<<<(N + B - 1) / B, B, 0, stream>>>(cnt, N);
  k_hist<<<(E + B - 1) / B, B, 0, stream>>>(dst, cnt, E);
  k_scan1<<<nb_scan, B, 0, stream>>>(cnt, offs, bsums, N);
  k_scan2<<<1, 1024, 0, stream>>>(bsums, nb_scan);
  k_scan3<<<(N + B - 1) / B, B, 0, stream>>>(offs, cursor, dis, cnt, bsums, N);
  k_scatter<<<(E + B - 1) / B, B, 0, stream>>>(src, dst, cursor, csr, E);
  k_gemm1<<<(N + 255) / 256, 256, 0, stream>>>(x, W1, dis, h1s, N);
  k_agg1n<<<(N + 3) / 4, B, 0, stream>>>(offs, cnt, csr, h1s, dis, b1, W2, h2s, N);
  k_agg2n<<<(N + 3) / 4, B, 0, stream>>>(offs, cnt, csr, h2s, dis, b2, out, N);
}

// Round 4
// 736.932 us; speedup vs baseline: 6.2428x; 1.6788x over previous
//
#include <hip/hip_runtime.h>
#include <math.h>

#define F_IN 1433
#define F_HID 16
#define F_OUT 7
#define KSPLIT 4
#define KCHUNK 384  // KSPLIT * KCHUNK >= F_IN; tiles of 32

// ---------------- zero int counters ----------------
__global__ __launch_bounds__(256) void k_zero(int* __restrict__ cnt, int N) {
  int i = blockIdx.x * 256 + threadIdx.x;
  if (i < N) cnt[i] = 0;
}

// ---------------- in-degree histogram over real edges ----------------
__global__ __launch_bounds__(256) void k_hist(const int* __restrict__ dst,
                                              int* __restrict__ cnt, int E) {
  int e = blockIdx.x * 256 + threadIdx.x;
  if (e < E) atomicAdd(&cnt[dst[e]], 1);
}

// ---------------- scan step 1: per-1024-block exclusive scan ----------------
__global__ __launch_bounds__(256) void k_scan1(const int* __restrict__ cnt,
                                               int* __restrict__ offs,
                                               int* __restrict__ bsums, int N) {
  __shared__ int sh[256];
  const int b = blockIdx.x, t = threadIdx.x;
  const int base = b * 1024 + t * 4;
  int v0 = 0, v1 = 0, v2 = 0, v3 = 0;
  if (base + 0 < N) v0 = cnt[base + 0];
  if (base + 1 < N) v1 = cnt[base + 1];
  if (base + 2 < N) v2 = cnt[base + 2];
  if (base + 3 < N) v3 = cnt[base + 3];
  const int s = v0 + v1 + v2 + v3;
  sh[t] = s;
  __syncthreads();
  for (int d = 1; d < 256; d <<= 1) {
    int x = (t >= d) ? sh[t - d] : 0;
    __syncthreads();
    sh[t] += x;
    __syncthreads();
  }
  const int incl = sh[t];
  const int excl = incl - s;
  if (t == 255) bsums[b] = incl;
  int o = excl;
  if (base + 0 < N) offs[base + 0] = o;
  o += v0;
  if (base + 1 < N) offs[base + 1] = o;
  o += v1;
  if (base + 2 < N) offs[base + 2] = o;
  o += v2;
  if (base + 3 < N) offs[base + 3] = o;
}

// ---------------- scan step 2: scan the block sums (1 block) ----------------
__global__ __launch_bounds__(1024) void k_scan2(int* __restrict__ bsums, int nb) {
  __shared__ int sh[1024];
  const int t = threadIdx.x;
  const int v = (t < nb) ? bsums[t] : 0;
  sh[t] = v;
  __syncthreads();
  for (int d = 1; d < 1024; d <<= 1) {
    int x = (t >= d) ? sh[t - d] : 0;
    __syncthreads();
    sh[t] += x;
    __syncthreads();
  }
  if (t < nb) bsums[t] = sh[t] - v;  // exclusive
}

// ---- scan step 3: finalize offsets, init cursor, dis = rsqrt(deg+1) --------
__global__ __launch_bounds__(256) void k_scan3(int* __restrict__ offs,
                                               int* __restrict__ cursor,
                                               float* __restrict__ dis,
                                               const int* __restrict__ cnt,
                                               const int* __restrict__ bsums,
                                               int N) {
  int i = blockIdx.x * 256 + threadIdx.x;
  if (i >= N) return;
  const int o = offs[i] + bsums[i >> 10];
  offs[i] = o;
  cursor[i] = o;
  dis[i] = rsqrtf((float)(cnt[i] + 1));  // +1 = self-loop
}

// ---------------- CSR scatter: csr[slot] = src, grouped by dst --------------
__global__ __launch_bounds__(256) void k_scatter(const int* __restrict__ src,
                                                 const int* __restrict__ dst,
                                                 int* __restrict__ cursor,
                                                 int* __restrict__ csr, int E) {
  int e = blockIdx.x * 256 + threadIdx.x;
  if (e >= E) return;
  const int d = dst[e];
  const int p = atomicAdd(&cursor[d], 1);
  csr[p] = src[e];
}

// ---- GEMM1 (K-split): part[c][row][j] = sum_{k in chunk c} x[row][k]*W1[k][j]
// grid.x = row-blocks, grid.y = K-chunk. Register-prefetch double buffer:
// tile t+1's 32 global loads are issued right after the barrier so they fly
// during tile t's 512-FMA compute phase.
__global__ __launch_bounds__(256) void k_gemm1(const float* __restrict__ x,
                                               const float* __restrict__ W1,
                                               float* __restrict__ part, int N) {
  __shared__ float xs[256 * 33];
  const int t = threadIdx.x;
  const int row0 = blockIdx.x * 256;
  const int row = row0 + t;
  const int kk = t & 31;
  const int r0 = t >> 5;
  const int cbase = blockIdx.y * KCHUNK;
  const int kend = min(cbase + KCHUNK, F_IN);

  float acc[F_HID];
#pragma unroll
  for (int j = 0; j < F_HID; ++j) acc[j] = 0.0f;

  float reg[32];
  // prologue: prefetch tile 0
  {
    const int k = cbase + kk;
    const bool kin = (k < kend);
#pragma unroll
    for (int i = 0; i < 32; ++i) {
      const int rg = row0 + r0 + 8 * i;
      reg[i] = (kin && rg < N) ? x[(size_t)rg * F_IN + k] : 0.0f;
    }
  }

  for (int k0 = cbase; k0 < kend; k0 += 32) {
    // stage regs -> LDS
#pragma unroll
    for (int i = 0; i < 32; ++i) xs[(r0 + 8 * i) * 33 + kk] = reg[i];
    __syncthreads();
    // prefetch next tile (overlaps with compute below)
    const int kn = k0 + 32;
    if (kn < kend) {
      const int k = kn + kk;
      const bool kin = (k < kend);
#pragma unroll
      for (int i = 0; i < 32; ++i) {
        const int rg = row0 + r0 + 8 * i;
        reg[i] = (kin && rg < N) ? x[(size_t)rg * F_IN + k] : 0.0f;
      }
    }
    // compute tile k0
    const int kw = min(32, kend - k0);
    const float* __restrict__ wp = W1 + (size_t)k0 * F_HID;
    if (kw == 32) {
#pragma unroll
      for (int c = 0; c < 32; ++c) {
        const float xv = xs[t * 33 + c];
#pragma unroll
        for (int j = 0; j < F_HID; ++j)
          acc[j] = fmaf(xv, wp[c * F_HID + j], acc[j]);
      }
    } else {
      for (int c = 0; c < kw; ++c) {
        const float xv = xs[t * 33 + c];
#pragma unroll
        for (int j = 0; j < F_HID; ++j)
          acc[j] = fmaf(xv, wp[c * F_HID + j], acc[j]);
      }
    }
    __syncthreads();
  }

  if (row < N) {
    float4* __restrict__ pp =
        (float4*)(part + ((size_t)blockIdx.y * N + row) * F_HID);
    pp[0] = make_float4(acc[0], acc[1], acc[2], acc[3]);
    pp[1] = make_float4(acc[4], acc[5], acc[6], acc[7]);
    pp[2] = make_float4(acc[8], acc[9], acc[10], acc[11]);
    pp[3] = make_float4(acc[12], acc[13], acc[14], acc[15]);
  }
}

// ---- reduce K-split partials + scale by dis: h1s = dis[row] * sum_c part ---
__global__ __launch_bounds__(256) void k_red(const float4* __restrict__ part,
                                             const float* __restrict__ dis,
                                             float4* __restrict__ h1s, int N) {
  const int idx = blockIdx.x * 256 + threadIdx.x;  // over N*4 float4s
  if (idx >= N * 4) return;
  const int row = idx >> 2;
  const size_t stride = (size_t)N * 4;
  float4 a = part[idx];
  float4 b = part[stride + idx];
  float4 c = part[2 * stride + idx];
  float4 d = part[3 * stride + idx];
  const float s = dis[row];
  float4 r;
  r.x = (a.x + b.x + c.x + d.x) * s;
  r.y = (a.y + b.y + c.y + d.y) * s;
  r.z = (a.z + b.z + c.z + d.z) * s;
  r.w = (a.w + b.w + c.w + d.w) * s;
  h1s[idx] = r;
}

// ---- layer1 gather + node update fused: one wave64 per dst node ------------
// lanes = 4 neighbor-groups x 16 features
__global__ __launch_bounds__(256) void k_agg1n(const int* __restrict__ offs,
                                               const int* __restrict__ cnt,
                                               const int* __restrict__ csr,
                                               const float* __restrict__ h1s,
                                               const float* __restrict__ dis,
                                               const float* __restrict__ b1,
                                               const float* __restrict__ W2,
                                               float* __restrict__ h2s, int N) {
  const int lane = threadIdx.x & 63;
  const int i = blockIdx.x * 4 + (threadIdx.x >> 6);
  if (i >= N) return;
  const int nb = lane >> 4;
  const int f = lane & 15;

  const int o0 = offs[i];
  const int d = cnt[i];
  float acc = 0.0f;
  for (int c = o0 + nb; c < o0 + d; c += 4) {
    const int s = csr[c];
    acc += h1s[(size_t)s * F_HID + f];
  }
  acc += __shfl_xor(acc, 16);
  acc += __shfl_xor(acc, 32);

  const float sd = dis[i];
  const float t = fmaxf(fmaf(acc + h1s[(size_t)i * F_HID + f], sd, b1[f]), 0.0f);

  float o[F_OUT];
#pragma unroll
  for (int j = 0; j < F_OUT; ++j) o[j] = t * W2[f * F_OUT + j];
#pragma unroll
  for (int dd = 1; dd < 16; dd <<= 1) {
#pragma unroll
    for (int j = 0; j < F_OUT; ++j) o[j] += __shfl_xor(o[j], dd);
  }
  if (lane == 0) {
    float* __restrict__ hp = h2s + (size_t)i * F_OUT;
#pragma unroll
    for (int j = 0; j < F_OUT; ++j) hp[j] = o[j] * sd;
  }
}

// ---- layer2 gather + bias + log_softmax fused: one wave64 per dst ----------
// lanes = 8 neighbor-groups x 8 feature slots (slot 7 inactive)
__global__ __launch_bounds__(256) void k_agg2n(const int* __restrict__ offs,
                                               const int* __restrict__ cnt,
                                               const int* __restrict__ csr,
                                               const float* __restrict__ h2s,
                                               const float* __restrict__ dis,
                                               const float* __restrict__ b2,
                                               float* __restrict__ out, int N) {
  const int lane = threadIdx.x & 63;
  const int i = blockIdx.x * 4 + (threadIdx.x >> 6);
  if (i >= N) return;
  const int nb = lane >> 3;
  const int f = lane & 7;

  const int o0 = offs[i];
  const int d = cnt[i];
  float acc = 0.0f;
  for (int c = o0 + nb; c < o0 + d; c += 8) {
    const int s = csr[c];
    if (f < F_OUT) acc += h2s[(size_t)s * F_OUT + f];
  }
  acc += __shfl_xor(acc, 8);
  acc += __shfl_xor(acc, 16);
  acc += __shfl_xor(acc, 32);

  float v = -1e30f;
  if (f < F_OUT)
    v = fmaf(acc + h2s[(size_t)i * F_OUT + f], dis[i], b2[f]);

  float m = v;
  m = fmaxf(m, __shfl_xor(m, 1));
  m = fmaxf(m, __shfl_xor(m, 2));
  m = fmaxf(m, __shfl_xor(m, 4));
  float ex = (f < F_OUT) ? expf(v - m) : 0.0f;
  float sum = ex;
  sum += __shfl_xor(sum, 1);
  sum += __shfl_xor(sum, 2);
  sum += __shfl_xor(sum, 4);
  const float r = v - m - logf(sum);
  if (f < F_OUT) out[(size_t)i * F_OUT + f] = r;
}

extern "C" void kernel_launch(void* const* d_in, const int* in_sizes, int n_in,
                              void* d_out, int out_size, void* d_ws,
                              size_t ws_size, hipStream_t stream) {
  const float* x = (const float*)d_in[0];
  const int* ei = (const int*)d_in[1];
  const float* W1 = (const float*)d_in[2];
  const float* b1 = (const float*)d_in[3];
  const float* W2 = (const float*)d_in[4];
  const float* b2 = (const float*)d_in[5];

  const int N = in_sizes[0] / F_IN;
  const int E = in_sizes[1] / 2;
  const int* src = ei;
  const int* dst = ei + E;

  // workspace layout (floats first for 16B alignment)
  float* h1s = (float*)d_ws;            // 16N
  float* h2s = h1s + (size_t)16 * N;    // 7N
  float* dis = h2s + (size_t)7 * N;     // N
  int* cnt = (int*)(dis + N);           // N
  int* offs = cnt + N;                  // N
  int* cursor = offs + N;               // N
  int* bsums = cursor + N;              // 1024
  // csr (E ints) and gemm partials (KSPLIT*16N floats) alias each other:
  // partials are consumed by k_red BEFORE k_scatter writes csr.
  float* part = (float*)(bsums + 1024);  // KSPLIT*16N floats
  int* csr = (int*)part;                 // E ints
  float* out = (float*)d_out;

  const int B = 256;
  const int nb_scan = (N + 1023) / 1024;
  const int nrb = (N + 255) / 256;

  k_zero<<<(N + B - 1) / B, B, 0, stream>>>(cnt, N);
  k_hist<<<(E + B - 1) / B, B, 0, stream>>>(dst, cnt, E);
  k_scan1<<<nb_scan, B, 0, stream>>>(cnt, offs, bsums, N);
  k_scan2<<<1, 1024, 0, stream>>>(bsums, nb_scan);
  k_scan3<<<(N + B - 1) / B, B, 0, stream>>>(offs, cursor, dis, cnt, bsums, N);
  dim3 g1(nrb, KSPLIT);
  k_gemm1<<<g1, 256, 0, stream>>>(x, W1, part, N);
  k_red<<<(N * 4 + B - 1) / B, B, 0, stream>>>((const float4*)part, dis,
                                               (float4*)h1s, N);
  k_scatter<<<(E + B - 1) / B, B, 0, stream>>>(src, dst, cursor, csr, E);
  k_agg1n<<<(N + 3) / 4, B, 0, stream>>>(offs, cnt, csr, h1s, dis, b1, W2, h2s, N);
  k_agg2n<<<(N + 3) / 4, B, 0, stream>>>(offs, cnt, csr, h2s, dis, b2, out, N);
}